// Round 2
// baseline (1396.903 us; speedup 1.0000x reference)
//
#include <hip/hip_runtime.h>

// Problem constants
#define DIMV   64
#define NEMB   1024
#define NROWS  262144          // B*T = 2048*128
#define DECAYF 0.99f
#define OMDF   0.01f           // 1 - decay
#define EPSF   1e-5f

// d_out layout (floats): quantize | loss | new_embed | new_cluster_size | new_embed_avg
#define OQ   0
#define OL   16777216
#define OE   16777217
#define ONC  16842753
#define OA   16843777

// d_ws layout (floats)
#define WS_E2    0        // 1024: ||e_k||^2
#define WS_CNT   1024     // 1024: counts
#define WS_ESUM  2048     // 65536: embed_sum [d][k]
#define WS_LOSS  67584    // 1: loss accumulator
#define WS_TOTAL 67585    // 1: sum(new_cluster_size)
#define WS_ET    67588    // 65536: embed transposed [k][d] (16B-aligned: 67588*4 % 16 == 0)

// ---------------------------------------------------------------- prep: transpose embed -> et[k][d], e2
__global__ void vq_prep(const float* __restrict__ embed, float* __restrict__ et,
                        float* __restrict__ e2)
{
    int idx = blockIdx.x * 256 + threadIdx.x;   // < 65536, idx = d*1024 + k
    int d = idx >> 10;
    int k = idx & (NEMB - 1);
    float v = embed[idx];           // coalesced read
    et[k * DIMV + d] = v;           // scattered write (256 KB total, negligible)
    // e2 via atomic-free second kernel is overkill; do a separate pass below
    (void)e2;
}

__global__ void vq_e2(const float* __restrict__ et, float* __restrict__ e2)
{
    // one wave-lane per code, et rows are contiguous
    int k = blockIdx.x * 256 + threadIdx.x;   // k < 1024
    const float4* ep = (const float4*)(et + k * DIMV);
    float s = 0.f;
    #pragma unroll
    for (int i = 0; i < 16; i++) {
        float4 v = ep[i];
        s = fmaf(v.x, v.x, fmaf(v.y, v.y, fmaf(v.z, v.z, fmaf(v.w, v.w, s))));
    }
    e2[k] = s;
}

// ---------------------------------------------------------------- main: argmin + gather + loss + EMA scatter
// No LDS. Codebook is read via wave-uniform addresses -> scalar loads (SGPR operand to v_fma).
__global__ __launch_bounds__(256, 4) void vq_main(
    const float* __restrict__ x, const int* __restrict__ mask,
    const float* __restrict__ et, const float* __restrict__ e2g,
    float* __restrict__ out, float* __restrict__ counts,
    float* __restrict__ esum, float* __restrict__ lossacc)
{
    const int tid = threadIdx.x;
    const int row = blockIdx.x * 256 + tid;

    // x row -> registers (16 x float4 = 64 VGPRs)
    float4 xv[16];
    {
        const float4* xp = (const float4*)(x + (size_t)row * DIMV);
        #pragma unroll
        for (int i = 0; i < 16; i++) xv[i] = xp[i];
    }
    float x2 = 0.f;
    #pragma unroll
    for (int i = 0; i < 16; i++)
        x2 += xv[i].x * xv[i].x + xv[i].y * xv[i].y + xv[i].z * xv[i].z + xv[i].w * xv[i].w;

    float best = 3.4e38f;
    int   bestk = 0;

    for (int kk = 0; kk < NEMB; kk++) {
        // wave-uniform address (depends only on loop counter) -> scalar loads
        const float4* ep = (const float4*)(et + (kk << 6));
        float ax = 0.f, ay = 0.f, az = 0.f, aw = 0.f;       // 4 chains for ILP
        #pragma unroll
        for (int i = 0; i < 16; i++) {
            float4 ev = ep[i];   // uniform: s_load_dwordx4, SGPR operand into v_fma
            ax = fmaf(xv[i].x, ev.x, ax);
            ay = fmaf(xv[i].y, ev.y, ay);
            az = fmaf(xv[i].z, ev.z, az);
            aw = fmaf(xv[i].w, ev.w, aw);
        }
        float dot  = (ax + ay) + (az + aw);
        float dist = (x2 - 2.0f * dot) + e2g[kk];  // same shape as np formula
        if (dist < best) { best = dist; bestk = kk; }  // strict < : first index wins
    }

    // ---- epilogue: gather code, straight-through write, loss, EMA scatter ----
    const bool valid = (mask[row] == 0);   // valid = ~mask
    float sq = 0.f;
    float4* qp = (float4*)(out + OQ + (size_t)row * DIMV);
    const float4* erow = (const float4*)(et + (bestk << 6));   // contiguous gather
    #pragma unroll
    for (int i = 0; i < 16; i++) {
        float4 xvv = xv[i];
        float4 ev  = erow[i];
        // replicate straight-through rounding: q = x + (e - x)
        float q0 = xvv.x + (ev.x - xvv.x);
        float q1 = xvv.y + (ev.y - xvv.y);
        float q2 = xvv.z + (ev.z - xvv.z);
        float q3 = xvv.w + (ev.w - xvv.w);
        float4 q4 = {q0, q1, q2, q3};
        qp[i] = q4;
        float d0 = q0 - xvv.x, d1 = q1 - xvv.y, d2 = q2 - xvv.z, d3 = q3 - xvv.w;
        sq += d0 * d0 + d1 * d1 + d2 * d2 + d3 * d3;
        if (valid) {
            atomicAdd(&esum[(4 * i + 0) * NEMB + bestk], xvv.x);
            atomicAdd(&esum[(4 * i + 1) * NEMB + bestk], xvv.y);
            atomicAdd(&esum[(4 * i + 2) * NEMB + bestk], xvv.z);
            atomicAdd(&esum[(4 * i + 3) * NEMB + bestk], xvv.w);
        }
    }
    if (valid) atomicAdd(&counts[bestk], 1.0f);

    // loss: wave-reduce then one atomic per wave
    float v = valid ? sq : 0.0f;
    #pragma unroll
    for (int off = 32; off > 0; off >>= 1) v += __shfl_down(v, off, 64);
    if ((tid & 63) == 0) atomicAdd(lossacc, v);
}

// ---------------------------------------------------------------- finalize A: cluster size, total, loss
__global__ __launch_bounds__(1024) void vq_finalA(
    const float* __restrict__ cluster_size, const float* __restrict__ counts,
    const float* __restrict__ lossacc, float* __restrict__ out,
    float* __restrict__ total_ws)
{
    __shared__ float s1[1024];  // sum of new_cluster_size
    __shared__ float s2[1024];  // sum of counts (= n_valid)
    int k = threadIdx.x;
    float c   = counts[k];
    float ncs = cluster_size[k] * DECAYF + OMDF * c;
    out[ONC + k] = ncs;
    s1[k] = ncs; s2[k] = c;
    __syncthreads();
    for (int off = 512; off > 0; off >>= 1) {
        if (k < off) { s1[k] += s1[k + off]; s2[k] += s2[k + off]; }
        __syncthreads();
    }
    if (k == 0) {
        total_ws[0] = s1[0];
        out[OL] = lossacc[0] / (s2[0] * (float)DIMV);
    }
}

// ---------------------------------------------------------------- finalize B: embed_avg, embed
__global__ void vq_finalB(const float* __restrict__ embed_avg,
                          const float* __restrict__ esum,
                          float* __restrict__ out,
                          const float* __restrict__ total_ws)
{
    int idx = blockIdx.x * 256 + threadIdx.x;  // < 65536, idx = d*1024 + k
    int k = idx & (NEMB - 1);
    float avg = embed_avg[idx] * DECAYF + OMDF * esum[idx];
    out[OA + idx] = avg;
    float ncs   = out[ONC + k];
    float total = *total_ws;
    float sm = (ncs + EPSF) / (total + (float)NEMB * EPSF) * total;
    out[OE + idx] = avg / sm;
}

// ---------------------------------------------------------------- launcher
extern "C" void kernel_launch(void* const* d_in, const int* in_sizes, int n_in,
                              void* d_out, int out_size, void* d_ws, size_t ws_size,
                              hipStream_t stream)
{
    const float* x            = (const float*)d_in[0];
    const int*   mask         = (const int*)d_in[1];
    const float* embed        = (const float*)d_in[2];
    const float* cluster_size = (const float*)d_in[3];
    const float* embed_avg    = (const float*)d_in[4];
    float* out = (float*)d_out;
    float* ws  = (float*)d_ws;

    // zero accumulators (counts, esum, loss, total)
    hipMemsetAsync(ws + WS_CNT, 0, (size_t)(WS_TOTAL + 1 - WS_CNT) * sizeof(float), stream);

    vq_prep<<<65536 / 256, 256, 0, stream>>>(embed, ws + WS_ET, ws + WS_E2);
    vq_e2<<<NEMB / 256, 256, 0, stream>>>(ws + WS_ET, ws + WS_E2);
    vq_main<<<NROWS / 256, 256, 0, stream>>>(x, mask, ws + WS_ET, ws + WS_E2, out,
                                             ws + WS_CNT, ws + WS_ESUM, ws + WS_LOSS);
    vq_finalA<<<1, 1024, 0, stream>>>(cluster_size, ws + WS_CNT, ws + WS_LOSS,
                                      out, ws + WS_TOTAL);
    vq_finalB<<<65536 / 256, 256, 0, stream>>>(embed_avg, ws + WS_ESUM, out, ws + WS_TOTAL);
}

// Round 3
// 1222.518 us; speedup vs baseline: 1.1426x; 1.1426x over previous
//
#include <hip/hip_runtime.h>

// Problem constants
#define DIMV   64
#define NEMB   1024
#define NROWS  262144          // B*T = 2048*128
#define DECAYF 0.99f
#define OMDF   0.01f           // 1 - decay
#define EPSF   1e-5f

// d_out layout (floats): quantize | loss | new_embed | new_cluster_size | new_embed_avg
#define OQ   0
#define OL   16777216
#define OE   16777217
#define ONC  16842753
#define OA   16843777

// d_ws layout (floats)
#define WS_E2    0        // 1024: ||e_k||^2
#define WS_CNT   1024     // 1024: counts
#define WS_ESUM  2048     // 65536: embed_sum [d][k]
#define WS_LOSS  67584    // 1: loss accumulator
#define WS_TOTAL 67585    // 1: sum(new_cluster_size)
#define WS_ET    67588    // 65536: embed transposed [k][d] (16B-aligned)

__device__ __forceinline__ float bcast_lane(float v, int lane) {
    return __int_as_float(__builtin_amdgcn_readlane(__float_as_int(v), lane));
}

// ---------------------------------------------------------------- prep: transpose embed -> et[k][d]
__global__ void vq_prep(const float* __restrict__ embed, float* __restrict__ et)
{
    int idx = blockIdx.x * 256 + threadIdx.x;   // < 65536, idx = d*1024 + k
    int d = idx >> 10;
    int k = idx & (NEMB - 1);
    et[k * DIMV + d] = embed[idx];
}

__global__ void vq_e2(const float* __restrict__ et, float* __restrict__ e2)
{
    int k = blockIdx.x * 256 + threadIdx.x;   // k < 1024
    const float4* ep = (const float4*)(et + k * DIMV);
    float s = 0.f;
    #pragma unroll
    for (int i = 0; i < 16; i++) {
        float4 v = ep[i];
        s = fmaf(v.x, v.x, fmaf(v.y, v.y, fmaf(v.z, v.z, fmaf(v.w, v.w, s))));
    }
    e2[k] = s;
}

// ---------------------------------------------------------------- main
// 4 rows/thread in VGPRs. Code stream: per-lane coalesced load (1 dword/lane =
// whole code vector per wave) prefetched 1 iter ahead, broadcast via v_readlane.
// No LDS, no uniform memory loads in the inner loop.
__global__ __launch_bounds__(64, 1) void vq_main(
    const float* __restrict__ x, const int* __restrict__ mask,
    const float* __restrict__ et, const float* __restrict__ e2g,
    float* __restrict__ out, float* __restrict__ counts,
    float* __restrict__ esum, float* __restrict__ lossacc)
{
    const int tid = threadIdx.x;                       // 0..63
    const int base_row = (blockIdx.x * 64 + tid) * 4;  // thread owns 4 rows

    // ---- load 4 rows of x into registers (float arrays -> pure VGPR after unroll)
    float xr[4][64];
    #pragma unroll
    for (int r = 0; r < 4; r++) {
        const float4* xp = (const float4*)(x + (size_t)(base_row + r) * DIMV);
        #pragma unroll
        for (int i = 0; i < 16; i++) {
            float4 t = xp[i];
            xr[r][4 * i + 0] = t.x; xr[r][4 * i + 1] = t.y;
            xr[r][4 * i + 2] = t.z; xr[r][4 * i + 3] = t.w;
        }
    }
    // x2 in round-1 order (sequential adds of 4-term groups)
    float x2[4];
    #pragma unroll
    for (int r = 0; r < 4; r++) {
        float s = 0.f;
        #pragma unroll
        for (int i = 0; i < 16; i++)
            s += xr[r][4*i]*xr[r][4*i] + xr[r][4*i+1]*xr[r][4*i+1]
               + xr[r][4*i+2]*xr[r][4*i+2] + xr[r][4*i+3]*xr[r][4*i+3];
        x2[r] = s;
    }

    float best[4]  = {3.4e38f, 3.4e38f, 3.4e38f, 3.4e38f};
    int   bestk[4] = {0, 0, 0, 0};

    float vcode  = et[tid];      // code 0, dim=lane
    float e2next = e2g[tid];     // e2 chunk 0, lane-wise

    for (int kc = 0; kc < NEMB; kc += 64) {
        float e2cur = e2next;
        int nchunk = (kc + 64 <= NEMB - 64) ? (kc + 64) : (NEMB - 64);
        e2next = e2g[nchunk + tid];

        for (int kk = 0; kk < 64; kk++) {
            const int k = kc + kk;
            const int knext = (k < NEMB - 1) ? (k + 1) : (NEMB - 1);
            float vnext = et[knext * DIMV + tid];   // prefetch next code (coalesced)

            // 4-chain accumulation per row, chain = j&3 (identical rounding to round-1)
            float a[4][4];
            #pragma unroll
            for (int r = 0; r < 4; r++)
                #pragma unroll
                for (int c = 0; c < 4; c++) a[r][c] = 0.f;

            #pragma unroll
            for (int j = 0; j < 64; j++) {
                float cj = bcast_lane(vcode, j);    // SGPR broadcast, no memory
                const int c = j & 3;
                a[0][c] = fmaf(cj, xr[0][j], a[0][c]);
                a[1][c] = fmaf(cj, xr[1][j], a[1][c]);
                a[2][c] = fmaf(cj, xr[2][j], a[2][c]);
                a[3][c] = fmaf(cj, xr[3][j], a[3][c]);
            }

            float e2k = bcast_lane(e2cur, kk);
            #pragma unroll
            for (int r = 0; r < 4; r++) {
                float dot  = (a[r][0] + a[r][1]) + (a[r][2] + a[r][3]);
                float dist = (x2[r] - 2.0f * dot) + e2k;   // np formula shape
                if (dist < best[r]) { best[r] = dist; bestk[r] = k; }  // strict <: first idx
            }
            vcode = vnext;
        }
    }

    // ---- epilogue: gather, straight-through write, loss, EMA scatter ----
    float lsum = 0.f;
    #pragma unroll
    for (int r = 0; r < 4; r++) {
        const int row = base_row + r;
        const bool valid = (mask[row] == 0);
        float4* qp = (float4*)(out + OQ + (size_t)row * DIMV);
        const float4* erow = (const float4*)(et + (bestk[r] << 6));
        float sq = 0.f;
        #pragma unroll
        for (int i = 0; i < 16; i++) {
            float x0 = xr[r][4*i+0], x1 = xr[r][4*i+1], x2v = xr[r][4*i+2], x3 = xr[r][4*i+3];
            float4 ev = erow[i];
            float q0 = x0 + (ev.x - x0);
            float q1 = x1 + (ev.y - x1);
            float q2 = x2v + (ev.z - x2v);
            float q3 = x3 + (ev.w - x3);
            float4 q4 = {q0, q1, q2, q3};
            qp[i] = q4;
            float d0 = q0 - x0, d1 = q1 - x1, d2 = q2 - x2v, d3 = q3 - x3;
            sq += d0 * d0 + d1 * d1 + d2 * d2 + d3 * d3;
            if (valid) {
                atomicAdd(&esum[(4 * i + 0) * NEMB + bestk[r]], x0);
                atomicAdd(&esum[(4 * i + 1) * NEMB + bestk[r]], x1);
                atomicAdd(&esum[(4 * i + 2) * NEMB + bestk[r]], x2v);
                atomicAdd(&esum[(4 * i + 3) * NEMB + bestk[r]], x3);
            }
        }
        if (valid) {
            atomicAdd(&counts[bestk[r]], 1.0f);
            lsum += sq;
        }
    }

    // loss: wave-reduce then one atomic per wave
    #pragma unroll
    for (int off = 32; off > 0; off >>= 1) lsum += __shfl_down(lsum, off, 64);
    if (tid == 0) atomicAdd(lossacc, lsum);
}

// ---------------------------------------------------------------- finalize A
__global__ __launch_bounds__(1024) void vq_finalA(
    const float* __restrict__ cluster_size, const float* __restrict__ counts,
    const float* __restrict__ lossacc, float* __restrict__ out,
    float* __restrict__ total_ws)
{
    __shared__ float s1[1024];
    __shared__ float s2[1024];
    int k = threadIdx.x;
    float c   = counts[k];
    float ncs = cluster_size[k] * DECAYF + OMDF * c;
    out[ONC + k] = ncs;
    s1[k] = ncs; s2[k] = c;
    __syncthreads();
    for (int off = 512; off > 0; off >>= 1) {
        if (k < off) { s1[k] += s1[k + off]; s2[k] += s2[k + off]; }
        __syncthreads();
    }
    if (k == 0) {
        total_ws[0] = s1[0];
        out[OL] = lossacc[0] / (s2[0] * (float)DIMV);
    }
}

// ---------------------------------------------------------------- finalize B
__global__ void vq_finalB(const float* __restrict__ embed_avg,
                          const float* __restrict__ esum,
                          float* __restrict__ out,
                          const float* __restrict__ total_ws)
{
    int idx = blockIdx.x * 256 + threadIdx.x;  // < 65536, idx = d*1024 + k
    int k = idx & (NEMB - 1);
    float avg = embed_avg[idx] * DECAYF + OMDF * esum[idx];
    out[OA + idx] = avg;
    float ncs   = out[ONC + k];
    float total = *total_ws;
    float sm = (ncs + EPSF) / (total + (float)NEMB * EPSF) * total;
    out[OE + idx] = avg / sm;
}

// ---------------------------------------------------------------- launcher
extern "C" void kernel_launch(void* const* d_in, const int* in_sizes, int n_in,
                              void* d_out, int out_size, void* d_ws, size_t ws_size,
                              hipStream_t stream)
{
    const float* x            = (const float*)d_in[0];
    const int*   mask         = (const int*)d_in[1];
    const float* embed        = (const float*)d_in[2];
    const float* cluster_size = (const float*)d_in[3];
    const float* embed_avg    = (const float*)d_in[4];
    float* out = (float*)d_out;
    float* ws  = (float*)d_ws;

    // zero accumulators (counts, esum, loss, total)
    hipMemsetAsync(ws + WS_CNT, 0, (size_t)(WS_TOTAL + 1 - WS_CNT) * sizeof(float), stream);

    vq_prep<<<65536 / 256, 256, 0, stream>>>(embed, ws + WS_ET);
    vq_e2<<<NEMB / 256, 256, 0, stream>>>(ws + WS_ET, ws + WS_E2);
    vq_main<<<NROWS / 256, 64, 0, stream>>>(x, mask, ws + WS_ET, ws + WS_E2, out,
                                            ws + WS_CNT, ws + WS_ESUM, ws + WS_LOSS);
    vq_finalA<<<1, 1024, 0, stream>>>(cluster_size, ws + WS_CNT, ws + WS_LOSS,
                                      out, ws + WS_TOTAL);
    vq_finalB<<<65536 / 256, 256, 0, stream>>>(embed_avg, ws + WS_ESUM, out, ws + WS_TOTAL);
}

// Round 4
// 833.932 us; speedup vs baseline: 1.6751x; 1.4660x over previous
//
#include <hip/hip_runtime.h>

typedef short short8 __attribute__((ext_vector_type(8)));
typedef float f32x16 __attribute__((ext_vector_type(16)));

// Problem constants
#define DIMV   64
#define NEMB   1024
#define NROWS  262144          // B*T = 2048*128
#define DECAYF 0.99f
#define OMDF   0.01f
#define EPSF   1e-5f

// d_out layout (floats): quantize | loss | new_embed | new_cluster_size | new_embed_avg
#define OQ   0
#define OL   16777216
#define OE   16777217
#define ONC  16842753
#define OA   16843777
// EH/EL (bf16 split codebook, MFMA-B-fragment order) live in the d_out tail:
// [OL, OL+32768) and [OL+32768, OL+65536) float-slots. Written by vq_prep_b,
// read only by vq_main, then fully overwritten by finalA/finalB. No overlap
// with quantize [0,16777216) or ONC (starts at OL+65537... = 16842753).
#define OEH  16777216
#define OEL  (16777216 + 32768)

// d_ws layout (floats) — same 532 KB footprint as rounds 1-3 (proven OK)
#define WS_E2    0        // 1024: ||e_k||^2
#define WS_CNT   1024     // 1024: counts
#define WS_ESUM  2048     // 65536: embed_sum [d][k]
#define WS_LOSS  67584    // 1
#define WS_TOTAL 67585    // 1
#define WS_ET    67588    // 65536: embed transposed [k][d] fp32

// RNE float->bf16 (no NaN in data), and back
__device__ __forceinline__ unsigned short f2bf(float f) {
    unsigned u = __float_as_uint(f);
    u = u + 0x7FFFu + ((u >> 16) & 1u);
    return (unsigned short)(u >> 16);
}
__device__ __forceinline__ float bf2f(unsigned short h) {
    return __uint_as_float(((unsigned)h) << 16);
}

// ---------------------------------------------------------------- prep: transpose embed -> et[k][d]
__global__ void vq_prep(const float* __restrict__ embed, float* __restrict__ et)
{
    int idx = blockIdx.x * 256 + threadIdx.x;   // < 65536, idx = d*1024 + k
    int d = idx >> 10;
    int k = idx & (NEMB - 1);
    et[k * DIMV + d] = embed[idx];
}

__global__ void vq_e2(const float* __restrict__ et, float* __restrict__ e2)
{
    int k = blockIdx.x * 256 + threadIdx.x;   // k < 1024
    const float4* ep = (const float4*)(et + k * DIMV);
    float s = 0.f;
    #pragma unroll
    for (int i = 0; i < 16; i++) {
        float4 v = ep[i];
        s = fmaf(v.x, v.x, fmaf(v.y, v.y, fmaf(v.z, v.z, fmaf(v.w, v.w, s))));
    }
    e2[k] = s;
}

// ---------------------------------------------------------------- prep: split codebook into bf16 hi/lo,
// pre-swizzled into 32x32x16 MFMA B-fragment order:
// frag(nt,s): lane L, elem j  <->  B[k = s*16 + (L>>5)*8 + j][n = nt*32 + (L&31)]
// stored as contiguous 1KB blocks: index = ((nt*4+s)*64 + L)*8 + j  (ushort)
__global__ void vq_prep_b(const float* __restrict__ embed,
                          unsigned short* __restrict__ eh,
                          unsigned short* __restrict__ el)
{
    int t = blockIdx.x * 256 + threadIdx.x;    // 0..65535
    int j  = t & 7;
    int L  = (t >> 3) & 63;
    int s  = (t >> 9) & 3;
    int nt = t >> 11;                          // 0..31
    int d    = s * 16 + (L >> 5) * 8 + j;
    int code = nt * 32 + (L & 31);
    float e = embed[d * NEMB + code];
    unsigned short hb = f2bf(e);
    eh[t] = hb;
    el[t] = f2bf(e - bf2f(hb));
}

// ---------------------------------------------------------------- main: MFMA distance + argmin + fused epilogue
// Wave owns 64 rows (2 M-tiles of 32). 3-pass split-bf16 MFMA, per-lane top-2
// integer keys, cross-lane reduce, conditional fp32 rescore, per-lane (1 row)
// gather/quantize/loss/EMA-atomics.
__global__ __launch_bounds__(256, 2) void vq_main(
    const float* __restrict__ x, const int* __restrict__ mask,
    const unsigned short* __restrict__ eh, const unsigned short* __restrict__ el,
    const float* __restrict__ et, const float* __restrict__ e2g,
    float* __restrict__ out, float* __restrict__ counts,
    float* __restrict__ esum, float* __restrict__ lossacc)
{
    const int tid  = threadIdx.x;
    const int lane = tid & 63;
    const int wid  = tid >> 6;
    const int wbase = blockIdx.x * 256 + wid * 64;   // wave's first row
    const int lm = lane & 31;    // m (A) / n (B) within tile
    const int lh = lane >> 5;    // k-half selector

    // ---- A fragments: xh/xl for 2 M-tiles x 4 K-steps. A[m=lane&31][k=(lane>>5)*8+j]
    short8 ah[2][4], al[2][4];
    #pragma unroll
    for (int mt = 0; mt < 2; mt++) {
        const float* xr = x + (size_t)(wbase + mt * 32 + lm) * DIMV + lh * 8;
        #pragma unroll
        for (int s = 0; s < 4; s++) {
            const float* xp = xr + s * 16;
            #pragma unroll
            for (int j = 0; j < 8; j++) {
                float f = xp[j];
                unsigned short hb = f2bf(f);
                ah[mt][s][j] = (short)hb;
                al[mt][s][j] = (short)f2bf(f - bf2f(hb));
            }
        }
    }

    // per-lane top-2 keys per (mtile, acc-reg); key = (q<<10)|k, q = trunc(2048*(e2-2dot))
    int b1[2][16], b2[2][16];
    #pragma unroll
    for (int mt = 0; mt < 2; mt++)
        #pragma unroll
        for (int r = 0; r < 16; r++) { b1[mt][r] = 0x7FFFFFFF; b2[mt][r] = 0x7FFFFFFF; }

    const short8* ehf = (const short8*)eh;
    const short8* elf = (const short8*)el;

    for (int nt = 0; nt < 32; nt++) {
        short8 bh[4], bl[4];
        #pragma unroll
        for (int s = 0; s < 4; s++) {
            bh[s] = ehf[(nt * 4 + s) * 64 + lane];
            bl[s] = elf[(nt * 4 + s) * 64 + lane];
        }
        const int   klane = nt * 32 + lm;
        const float e2s   = e2g[klane] * 2048.0f;

        f32x16 acc0, acc1;
        #pragma unroll
        for (int i = 0; i < 16; i++) { acc0[i] = 0.0f; acc1[i] = 0.0f; }

        #pragma unroll
        for (int s = 0; s < 4; s++) {   // pass hh
            acc0 = __builtin_amdgcn_mfma_f32_32x32x16_bf16(ah[0][s], bh[s], acc0, 0, 0, 0);
            acc1 = __builtin_amdgcn_mfma_f32_32x32x16_bf16(ah[1][s], bh[s], acc1, 0, 0, 0);
        }
        #pragma unroll
        for (int s = 0; s < 4; s++) {   // pass hl
            acc0 = __builtin_amdgcn_mfma_f32_32x32x16_bf16(ah[0][s], bl[s], acc0, 0, 0, 0);
            acc1 = __builtin_amdgcn_mfma_f32_32x32x16_bf16(ah[1][s], bl[s], acc1, 0, 0, 0);
        }
        #pragma unroll
        for (int s = 0; s < 4; s++) {   // pass lh
            acc0 = __builtin_amdgcn_mfma_f32_32x32x16_bf16(al[0][s], bh[s], acc0, 0, 0, 0);
            acc1 = __builtin_amdgcn_mfma_f32_32x32x16_bf16(al[1][s], bh[s], acc1, 0, 0, 0);
        }

        #pragma unroll
        for (int r = 0; r < 16; r++) {
            int q0   = (int)fmaf(acc0[r], -4096.0f, e2s);     // 2048*(e2-2dot), trunc
            int key0 = (int)(((unsigned)q0) << 10) | klane;
            int lo0 = min(b1[0][r], key0), hi0 = max(b1[0][r], key0);
            b1[0][r] = lo0; b2[0][r] = min(b2[0][r], hi0);

            int q1   = (int)fmaf(acc1[r], -4096.0f, e2s);
            int key1 = (int)(((unsigned)q1) << 10) | klane;
            int lo1 = min(b1[1][r], key1), hi1 = max(b1[1][r], key1);
            b1[1][r] = lo1; b2[1][r] = min(b2[1][r], hi1);
        }
    }

    // ---- cross-lane reduction (per half-wave = 32 lanes sharing a row) ----
    int sm1 = 0x7FFFFFFF, sm2 = 0x7FFFFFFF, sc = 1;
    unsigned long long hm = (lane < 32) ? 0xFFFFFFFFull : 0xFFFFFFFF00000000ull;
    #pragma unroll
    for (int mt = 0; mt < 2; mt++) {
        #pragma unroll
        for (int r = 0; r < 16; r++) {
            int v1 = b1[mt][r], v2 = b2[mt][r];
            #pragma unroll
            for (int m = 1; m <= 16; m <<= 1) {
                int o1 = __shfl_xor(v1, m, 64);
                int o2 = __shfl_xor(v2, m, 64);
                int lo = min(v1, o1), hi = max(v1, o1);
                v1 = lo;
                v2 = min(min(v2, o2), hi);
            }
            // in-window count (window = 41/2048 ~= 0.02 in distance units)
            int thr = (v1 >> 10) + 41;
            bool in1 = (b1[mt][r] >> 10) <= thr;
            bool in2 = (b2[mt][r] >> 10) <= thr;
            unsigned long long B1 = __ballot(in1), B2 = __ballot(in2);
            int cnt = (int)__popcll(B1 & hm) + (int)__popcll(B2 & hm);
            // distribute: half0 result -> row r0, half1 result -> row r0+4
            int w1a = __shfl(v1, 0, 64),  w2a = __shfl(v2, 0, 64),  ca = __shfl(cnt, 0, 64);
            int w1b = __shfl(v1, 32, 64), w2b = __shfl(v2, 32, 64), cb = __shfl(cnt, 32, 64);
            int r0 = mt * 32 + (r & 3) + 8 * (r >> 2);
            if (lane == r0)     { sm1 = w1a; sm2 = w2a; sc = ca; }
            if (lane == r0 + 4) { sm1 = w1b; sm2 = w2b; sc = cb; }
        }
    }

    // ---- per-lane epilogue: lane owns row wbase+lane ----
    const int row = wbase + lane;
    float4 xv[16];
    {
        const float4* xp = (const float4*)(x + (size_t)row * DIMV);
        #pragma unroll
        for (int i = 0; i < 16; i++) xv[i] = xp[i];
    }

    int kw = sm1 & 1023;
    if (sc >= 2) {
        // exact fp32 rescore, round-1 op order
        float x2 = 0.f;
        #pragma unroll
        for (int i = 0; i < 16; i++)
            x2 += xv[i].x * xv[i].x + xv[i].y * xv[i].y + xv[i].z * xv[i].z + xv[i].w * xv[i].w;

        auto fdist = [&](int k) -> float {
            const float4* ep = (const float4*)(et + (k << 6));
            float ax = 0.f, ay = 0.f, az = 0.f, aw = 0.f;
            #pragma unroll
            for (int i = 0; i < 16; i++) {
                float4 ev = ep[i];
                ax = fmaf(xv[i].x, ev.x, ax);
                ay = fmaf(xv[i].y, ev.y, ay);
                az = fmaf(xv[i].z, ev.z, az);
                aw = fmaf(xv[i].w, ev.w, aw);
            }
            float dot = (ax + ay) + (az + aw);
            return (x2 - 2.0f * dot) + e2g[k];
        };

        if (sc >= 3) {
            // near-impossible fallback: exact full scan, np first-index rule
            float bd = 3.4e38f; int bk = 0;
            for (int k = 0; k < NEMB; k++) {
                float d = fdist(k);
                if (d < bd) { bd = d; bk = k; }
            }
            kw = bk;
        } else {
            int k2 = sm2 & 1023;
            float d1 = fdist(kw);
            float d2 = fdist(k2);
            if (d2 < d1 || (d2 == d1 && k2 < kw)) kw = k2;
        }
    }

    const bool valid = (mask[row] == 0);   // valid = ~mask
    float sq = 0.f;
    float4* qp = (float4*)(out + OQ + (size_t)row * DIMV);
    const float4* erow = (const float4*)(et + (kw << 6));
    #pragma unroll
    for (int i = 0; i < 16; i++) {
        float4 xvv = xv[i];
        float4 ev  = erow[i];
        float q0 = xvv.x + (ev.x - xvv.x);
        float q1 = xvv.y + (ev.y - xvv.y);
        float q2 = xvv.z + (ev.z - xvv.z);
        float q3 = xvv.w + (ev.w - xvv.w);
        float4 q4 = {q0, q1, q2, q3};
        qp[i] = q4;
        float d0 = q0 - xvv.x, d1 = q1 - xvv.y, d2 = q2 - xvv.z, d3 = q3 - xvv.w;
        sq += d0 * d0 + d1 * d1 + d2 * d2 + d3 * d3;
        if (valid) {
            atomicAdd(&esum[(4 * i + 0) * NEMB + kw], xvv.x);
            atomicAdd(&esum[(4 * i + 1) * NEMB + kw], xvv.y);
            atomicAdd(&esum[(4 * i + 2) * NEMB + kw], xvv.z);
            atomicAdd(&esum[(4 * i + 3) * NEMB + kw], xvv.w);
        }
    }
    if (valid) atomicAdd(&counts[kw], 1.0f);

    float v = valid ? sq : 0.0f;
    #pragma unroll
    for (int off = 32; off > 0; off >>= 1) v += __shfl_down(v, off, 64);
    if (lane == 0) atomicAdd(lossacc, v);
}

// ---------------------------------------------------------------- finalize A
__global__ __launch_bounds__(1024) void vq_finalA(
    const float* __restrict__ cluster_size, const float* __restrict__ counts,
    const float* __restrict__ lossacc, float* __restrict__ out,
    float* __restrict__ total_ws)
{
    __shared__ float s1[1024];
    __shared__ float s2[1024];
    int k = threadIdx.x;
    float c   = counts[k];
    float ncs = cluster_size[k] * DECAYF + OMDF * c;
    out[ONC + k] = ncs;
    s1[k] = ncs; s2[k] = c;
    __syncthreads();
    for (int off = 512; off > 0; off >>= 1) {
        if (k < off) { s1[k] += s1[k + off]; s2[k] += s2[k + off]; }
        __syncthreads();
    }
    if (k == 0) {
        total_ws[0] = s1[0];
        out[OL] = lossacc[0] / (s2[0] * (float)DIMV);
    }
}

// ---------------------------------------------------------------- finalize B
__global__ void vq_finalB(const float* __restrict__ embed_avg,
                          const float* __restrict__ esum,
                          float* __restrict__ out,
                          const float* __restrict__ total_ws)
{
    int idx = blockIdx.x * 256 + threadIdx.x;  // < 65536, idx = d*1024 + k
    int k = idx & (NEMB - 1);
    float avg = embed_avg[idx] * DECAYF + OMDF * esum[idx];
    out[OA + idx] = avg;
    float ncs   = out[ONC + k];
    float total = *total_ws;
    float sm = (ncs + EPSF) / (total + (float)NEMB * EPSF) * total;
    out[OE + idx] = avg / sm;
}

// ---------------------------------------------------------------- launcher
extern "C" void kernel_launch(void* const* d_in, const int* in_sizes, int n_in,
                              void* d_out, int out_size, void* d_ws, size_t ws_size,
                              hipStream_t stream)
{
    const float* x            = (const float*)d_in[0];
    const int*   mask         = (const int*)d_in[1];
    const float* embed        = (const float*)d_in[2];
    const float* cluster_size = (const float*)d_in[3];
    const float* embed_avg    = (const float*)d_in[4];
    float* out = (float*)d_out;
    float* ws  = (float*)d_ws;

    unsigned short* eh = (unsigned short*)(out + OEH);
    unsigned short* el = (unsigned short*)(out + OEL);

    // zero accumulators (counts, esum, loss, total)
    hipMemsetAsync(ws + WS_CNT, 0, (size_t)(WS_TOTAL + 1 - WS_CNT) * sizeof(float), stream);

    vq_prep<<<65536 / 256, 256, 0, stream>>>(embed, ws + WS_ET);
    vq_e2<<<NEMB / 256, 256, 0, stream>>>(ws + WS_ET, ws + WS_E2);
    vq_prep_b<<<65536 / 256, 256, 0, stream>>>(embed, eh, el);
    vq_main<<<NROWS / 256, 256, 0, stream>>>(x, mask, eh, el, ws + WS_ET, ws + WS_E2,
                                             out, ws + WS_CNT, ws + WS_ESUM, ws + WS_LOSS);
    vq_finalA<<<1, 1024, 0, stream>>>(cluster_size, ws + WS_CNT, ws + WS_LOSS,
                                      out, ws + WS_TOTAL);
    vq_finalB<<<65536 / 256, 256, 0, stream>>>(embed_avg, ws + WS_ESUM, out, ws + WS_TOTAL);
}

// Round 5
// 760.528 us; speedup vs baseline: 1.8368x; 1.0965x over previous
//
#include <hip/hip_runtime.h>

typedef short short8 __attribute__((ext_vector_type(8)));
typedef float f32x16 __attribute__((ext_vector_type(16)));

// Problem constants
#define DIMV   64
#define NEMB   1024
#define NROWS  262144          // B*T = 2048*128
#define DECAYF 0.99f
#define OMDF   0.01f
#define EPSF   1e-5f

// d_out layout (floats): quantize | loss | new_embed | new_cluster_size | new_embed_avg
#define OQ   0
#define OL   16777216
#define OE   16777217
#define ONC  16842753
#define OA   16843777
// EH/EL (bf16 split codebook, MFMA-B-fragment order) live in the d_out tail:
// written by vq_prep_b, read by vq_main, then overwritten by finalA/finalB.
#define OEH  16777216
#define OEL  (16777216 + 32768)

// d_ws layout (floats)
#define WS_E2    0        // 1024: ||e_k||^2
#define WS_CNT   1024     // 1024: counts
#define WS_ESUM  2048     // 65536: embed_sum, K-MAJOR: [k][d]  (atomic line locality)
#define WS_LOSS  67584    // 1
#define WS_TOTAL 67585    // 1
#define WS_ET    67588    // 65536: embed transposed [k][d] fp32

// RNE float->bf16 (no NaN in data), and back
__device__ __forceinline__ unsigned short f2bf(float f) {
    unsigned u = __float_as_uint(f);
    u = u + 0x7FFFu + ((u >> 16) & 1u);
    return (unsigned short)(u >> 16);
}
__device__ __forceinline__ float bf2f(unsigned short h) {
    return __uint_as_float(((unsigned)h) << 16);
}

// ---------------------------------------------------------------- prep: transpose embed -> et[k][d]
__global__ void vq_prep(const float* __restrict__ embed, float* __restrict__ et)
{
    int idx = blockIdx.x * 256 + threadIdx.x;   // < 65536, idx = d*1024 + k
    int d = idx >> 10;
    int k = idx & (NEMB - 1);
    et[k * DIMV + d] = embed[idx];
}

__global__ void vq_e2(const float* __restrict__ et, float* __restrict__ e2)
{
    int k = blockIdx.x * 256 + threadIdx.x;   // k < 1024
    const float4* ep = (const float4*)(et + k * DIMV);
    float s = 0.f;
    #pragma unroll
    for (int i = 0; i < 16; i++) {
        float4 v = ep[i];
        s = fmaf(v.x, v.x, fmaf(v.y, v.y, fmaf(v.z, v.z, fmaf(v.w, v.w, s))));
    }
    e2[k] = s;
}

// ---------------------------------------------------------------- prep: split codebook into bf16 hi/lo,
// pre-swizzled into 32x32x16 MFMA B-fragment order:
// frag(nt,s): lane L, elem j  <->  B[k = s*16 + (L>>5)*8 + j][n = nt*32 + (L&31)]
__global__ void vq_prep_b(const float* __restrict__ embed,
                          unsigned short* __restrict__ eh,
                          unsigned short* __restrict__ el)
{
    int t = blockIdx.x * 256 + threadIdx.x;    // 0..65535
    int j  = t & 7;
    int L  = (t >> 3) & 63;
    int s  = (t >> 9) & 3;
    int nt = t >> 11;                          // 0..31
    int d    = s * 16 + (L >> 5) * 8 + j;
    int code = nt * 32 + (L & 31);
    float e = embed[d * NEMB + code];
    unsigned short hb = f2bf(e);
    eh[t] = hb;
    el[t] = f2bf(e - bf2f(hb));
}

// ---------------------------------------------------------------- main
__global__ __launch_bounds__(256, 2) void vq_main(
    const float* __restrict__ x, const int* __restrict__ mask,
    const unsigned short* __restrict__ eh, const unsigned short* __restrict__ el,
    const float* __restrict__ et, const float* __restrict__ e2g,
    float* __restrict__ out, float* __restrict__ counts,
    float* __restrict__ esum, float* __restrict__ lossacc)
{
    const int tid  = threadIdx.x;
    const int lane = tid & 63;
    const int wid  = tid >> 6;
    const int wbase = blockIdx.x * 256 + wid * 64;   // wave's first row
    const int lm = lane & 31;    // m (A) / n (B) within tile
    const int lh = lane >> 5;    // k-half selector

    // ---- A fragments: xh/xl for 2 M-tiles x 4 K-steps. A[m=lane&31][k=(lane>>5)*8+j]
    short8 ah[2][4], al[2][4];
    #pragma unroll
    for (int mt = 0; mt < 2; mt++) {
        const float* xr = x + (size_t)(wbase + mt * 32 + lm) * DIMV + lh * 8;
        #pragma unroll
        for (int s = 0; s < 4; s++) {
            const float* xp = xr + s * 16;
            #pragma unroll
            for (int j = 0; j < 8; j++) {
                float f = xp[j];
                unsigned short hb = f2bf(f);
                ah[mt][s][j] = (short)hb;
                al[mt][s][j] = (short)f2bf(f - bf2f(hb));
            }
        }
    }

    // per-lane top-2 keys per (mtile, acc-reg); key = (q<<10)|k, q = trunc(2048*(e2-2dot))
    int b1[2][16], b2[2][16];
    #pragma unroll
    for (int mt = 0; mt < 2; mt++)
        #pragma unroll
        for (int r = 0; r < 16; r++) { b1[mt][r] = 0x7FFFFFFF; b2[mt][r] = 0x7FFFFFFF; }

    const short8* ehf = (const short8*)eh;
    const short8* elf = (const short8*)el;

    for (int nt = 0; nt < 32; nt++) {
        short8 bh[4], bl[4];
        #pragma unroll
        for (int s = 0; s < 4; s++) {
            bh[s] = ehf[(nt * 4 + s) * 64 + lane];
            bl[s] = elf[(nt * 4 + s) * 64 + lane];
        }
        const int   klane = nt * 32 + lm;
        const float e2s   = e2g[klane] * 2048.0f;

        f32x16 acc0, acc1;
        #pragma unroll
        for (int i = 0; i < 16; i++) { acc0[i] = 0.0f; acc1[i] = 0.0f; }

        #pragma unroll
        for (int s = 0; s < 4; s++) {   // pass hh
            acc0 = __builtin_amdgcn_mfma_f32_32x32x16_bf16(ah[0][s], bh[s], acc0, 0, 0, 0);
            acc1 = __builtin_amdgcn_mfma_f32_32x32x16_bf16(ah[1][s], bh[s], acc1, 0, 0, 0);
        }
        #pragma unroll
        for (int s = 0; s < 4; s++) {   // pass hl
            acc0 = __builtin_amdgcn_mfma_f32_32x32x16_bf16(ah[0][s], bl[s], acc0, 0, 0, 0);
            acc1 = __builtin_amdgcn_mfma_f32_32x32x16_bf16(ah[1][s], bl[s], acc1, 0, 0, 0);
        }
        #pragma unroll
        for (int s = 0; s < 4; s++) {   // pass lh
            acc0 = __builtin_amdgcn_mfma_f32_32x32x16_bf16(al[0][s], bh[s], acc0, 0, 0, 0);
            acc1 = __builtin_amdgcn_mfma_f32_32x32x16_bf16(al[1][s], bh[s], acc1, 0, 0, 0);
        }

        #pragma unroll
        for (int r = 0; r < 16; r++) {
            int q0   = (int)fmaf(acc0[r], -4096.0f, e2s);     // 2048*(e2-2dot), trunc
            int key0 = (int)(((unsigned)q0) << 10) | klane;
            int lo0 = min(b1[0][r], key0), hi0 = max(b1[0][r], key0);
            b1[0][r] = lo0; b2[0][r] = min(b2[0][r], hi0);

            int q1   = (int)fmaf(acc1[r], -4096.0f, e2s);
            int key1 = (int)(((unsigned)q1) << 10) | klane;
            int lo1 = min(b1[1][r], key1), hi1 = max(b1[1][r], key1);
            b1[1][r] = lo1; b2[1][r] = min(b2[1][r], hi1);
        }
    }

    // ---- cross-lane reduction (per half-wave = 32 lanes sharing a row) ----
    int sm1 = 0x7FFFFFFF, sm2 = 0x7FFFFFFF, sc = 1;
    unsigned long long hm = (lane < 32) ? 0xFFFFFFFFull : 0xFFFFFFFF00000000ull;
    #pragma unroll
    for (int mt = 0; mt < 2; mt++) {
        #pragma unroll
        for (int r = 0; r < 16; r++) {
            int v1 = b1[mt][r], v2 = b2[mt][r];
            #pragma unroll
            for (int m = 1; m <= 16; m <<= 1) {
                int o1 = __shfl_xor(v1, m, 64);
                int o2 = __shfl_xor(v2, m, 64);
                int lo = min(v1, o1), hi = max(v1, o1);
                v1 = lo;
                v2 = min(min(v2, o2), hi);
            }
            int thr = (v1 >> 10) + 41;   // window = 41/2048 ~= 0.02
            bool in1 = (b1[mt][r] >> 10) <= thr;
            bool in2 = (b2[mt][r] >> 10) <= thr;
            unsigned long long B1 = __ballot(in1), B2 = __ballot(in2);
            int cnt = (int)__popcll(B1 & hm) + (int)__popcll(B2 & hm);
            int w1a = __shfl(v1, 0, 64),  w2a = __shfl(v2, 0, 64),  ca = __shfl(cnt, 0, 64);
            int w1b = __shfl(v1, 32, 64), w2b = __shfl(v2, 32, 64), cb = __shfl(cnt, 32, 64);
            int r0 = mt * 32 + (r & 3) + 8 * (r >> 2);
            if (lane == r0)     { sm1 = w1a; sm2 = w2a; sc = ca; }
            if (lane == r0 + 4) { sm1 = w1b; sm2 = w2b; sc = cb; }
        }
    }

    // ---- per-lane epilogue: lane owns row wbase+lane ----
    const int row = wbase + lane;
    float4 xv[16];
    {
        const float4* xp = (const float4*)(x + (size_t)row * DIMV);
        #pragma unroll
        for (int i = 0; i < 16; i++) xv[i] = xp[i];
    }

    int kw = sm1 & 1023;
    if (sc >= 2) {
        float x2 = 0.f;
        #pragma unroll
        for (int i = 0; i < 16; i++)
            x2 += xv[i].x * xv[i].x + xv[i].y * xv[i].y + xv[i].z * xv[i].z + xv[i].w * xv[i].w;

        auto fdist = [&](int k) -> float {
            const float4* ep = (const float4*)(et + (k << 6));
            float ax = 0.f, ay = 0.f, az = 0.f, aw = 0.f;
            #pragma unroll
            for (int i = 0; i < 16; i++) {
                float4 ev = ep[i];
                ax = fmaf(xv[i].x, ev.x, ax);
                ay = fmaf(xv[i].y, ev.y, ay);
                az = fmaf(xv[i].z, ev.z, az);
                aw = fmaf(xv[i].w, ev.w, aw);
            }
            float dot = (ax + ay) + (az + aw);
            return (x2 - 2.0f * dot) + e2g[k];
        };

        if (sc >= 3) {
            float bd = 3.4e38f; int bk = 0;
            for (int k = 0; k < NEMB; k++) {
                float d = fdist(k);
                if (d < bd) { bd = d; bk = k; }
            }
            kw = bk;
        } else {
            int k2 = sm2 & 1023;
            float d1 = fdist(kw);
            float d2 = fdist(k2);
            if (d2 < d1 || (d2 == d1 && k2 < kw)) kw = k2;
        }
    }

    const bool valid = (mask[row] == 0);   // valid = ~mask
    float sq = 0.f;
    float4* qp = (float4*)(out + OQ + (size_t)row * DIMV);
    const float4* erow = (const float4*)(et + (kw << 6));
    #pragma unroll
    for (int i = 0; i < 16; i++) {
        float4 xvv = xv[i];
        float4 ev  = erow[i];
        float q0 = xvv.x + (ev.x - xvv.x);
        float q1 = xvv.y + (ev.y - xvv.y);
        float q2 = xvv.z + (ev.z - xvv.z);
        float q3 = xvv.w + (ev.w - xvv.w);
        float4 q4 = {q0, q1, q2, q3};
        qp[i] = q4;
        float d0 = q0 - xvv.x, d1 = q1 - xvv.y, d2 = q2 - xvv.z, d3 = q3 - xvv.w;
        sq += d0 * d0 + d1 * d1 + d2 * d2 + d3 * d3;
    }
    if (valid) atomicAdd(&counts[kw], 1.0f);

    // ---- wave-transposed EMA scatter: one atomic instruction per row,
    // 64 lanes = 64 contiguous dims of esum[k][d] (4 cache lines, not ~40).
    // valid flag broadcast -> wave-uniform branch skips masked rows entirely.
    #pragma unroll 4
    for (int j = 0; j < 64; j++) {
        int kj = __shfl(kw, j, 64);
        int vj = __shfl(valid ? 1 : 0, j, 64);
        if (vj) {
            float xjl = x[(size_t)(wbase + j) * DIMV + lane];   // coalesced, L1-hot
            atomicAdd(&esum[(kj << 6) + lane], xjl);
        }
    }

    float v = valid ? sq : 0.0f;
    #pragma unroll
    for (int off = 32; off > 0; off >>= 1) v += __shfl_down(v, off, 64);
    if (lane == 0) atomicAdd(lossacc, v);
}

// ---------------------------------------------------------------- finalize A
__global__ __launch_bounds__(1024) void vq_finalA(
    const float* __restrict__ cluster_size, const float* __restrict__ counts,
    const float* __restrict__ lossacc, float* __restrict__ out,
    float* __restrict__ total_ws)
{
    __shared__ float s1[1024];
    __shared__ float s2[1024];
    int k = threadIdx.x;
    float c   = counts[k];
    float ncs = cluster_size[k] * DECAYF + OMDF * c;
    out[ONC + k] = ncs;
    s1[k] = ncs; s2[k] = c;
    __syncthreads();
    for (int off = 512; off > 0; off >>= 1) {
        if (k < off) { s1[k] += s1[k + off]; s2[k] += s2[k + off]; }
        __syncthreads();
    }
    if (k == 0) {
        total_ws[0] = s1[0];
        out[OL] = lossacc[0] / (s2[0] * (float)DIMV);
    }
}

// ---------------------------------------------------------------- finalize B (esum is k-major now)
__global__ void vq_finalB(const float* __restrict__ embed_avg,
                          const float* __restrict__ esum,
                          float* __restrict__ out,
                          const float* __restrict__ total_ws)
{
    int idx = blockIdx.x * 256 + threadIdx.x;  // < 65536, idx = d*1024 + k
    int k = idx & (NEMB - 1);
    int d = idx >> 10;
    float avg = embed_avg[idx] * DECAYF + OMDF * esum[(k << 6) + d];
    out[OA + idx] = avg;
    float ncs   = out[ONC + k];
    float total = *total_ws;
    float sm = (ncs + EPSF) / (total + (float)NEMB * EPSF) * total;
    out[OE + idx] = avg / sm;
}

// ---------------------------------------------------------------- launcher
extern "C" void kernel_launch(void* const* d_in, const int* in_sizes, int n_in,
                              void* d_out, int out_size, void* d_ws, size_t ws_size,
                              hipStream_t stream)
{
    const float* x            = (const float*)d_in[0];
    const int*   mask         = (const int*)d_in[1];
    const float* embed        = (const float*)d_in[2];
    const float* cluster_size = (const float*)d_in[3];
    const float* embed_avg    = (const float*)d_in[4];
    float* out = (float*)d_out;
    float* ws  = (float*)d_ws;

    unsigned short* eh = (unsigned short*)(out + OEH);
    unsigned short* el = (unsigned short*)(out + OEL);

    // zero accumulators (counts, esum, loss, total)
    hipMemsetAsync(ws + WS_CNT, 0, (size_t)(WS_TOTAL + 1 - WS_CNT) * sizeof(float), stream);

    vq_prep<<<65536 / 256, 256, 0, stream>>>(embed, ws + WS_ET);
    vq_e2<<<NEMB / 256, 256, 0, stream>>>(ws + WS_ET, ws + WS_E2);
    vq_prep_b<<<65536 / 256, 256, 0, stream>>>(embed, eh, el);
    vq_main<<<NROWS / 256, 256, 0, stream>>>(x, mask, eh, el, ws + WS_ET, ws + WS_E2,
                                             out, ws + WS_CNT, ws + WS_ESUM, ws + WS_LOSS);
    vq_finalA<<<1, 1024, 0, stream>>>(cluster_size, ws + WS_CNT, ws + WS_LOSS,
                                      out, ws + WS_TOTAL);
    vq_finalB<<<65536 / 256, 256, 0, stream>>>(embed_avg, ws + WS_ESUM, out, ws + WS_TOTAL);
}